// Round 5
// baseline (1368.072 us; speedup 1.0000x reference)
//
#include <hip/hip_runtime.h>
#include <hip/hip_bf16.h>

#define BB 4
#define SS 4096
#define EE 64
#define DD 512
#define QBLK 64
#define KVBLK 32
#define NIT2 64  // iters per block (half the KV range)

typedef __attribute__((ext_vector_type(4))) float f32x4;
typedef __attribute__((ext_vector_type(8))) _Float16 f16x8;
typedef unsigned short u16;
typedef unsigned int u32;

__device__ __forceinline__ u16 f2h(float f) {
  _Float16 h = (_Float16)f;
  return __builtin_bit_cast(u16, h);
}
__device__ __forceinline__ float h2f(u16 b) {
  return (float)__builtin_bit_cast(_Float16, b);
}

// ---------------- K1: qkv projection (fp32 VALU), emit fp16 ----------------
__global__ __launch_bounds__(256) void qkv_proj(
    const float* __restrict__ x,
    const float* __restrict__ Wq, const float* __restrict__ bq,
    const float* __restrict__ Wk, const float* __restrict__ bk,
    const float* __restrict__ Wv, const float* __restrict__ bv,
    u16* __restrict__ qb, u16* __restrict__ kb, u16* __restrict__ vb) {
  __shared__ float xs[32][EE];
  const int tid = threadIdx.x;
  const int row0 = blockIdx.x * 32;
  const float* W;
  const float* bias;
  u16* dst;
  if (blockIdx.y == 0) { W = Wq; bias = bq; dst = qb; }
  else if (blockIdx.y == 1) { W = Wk; bias = bk; dst = kb; }
  else { W = Wv; bias = bv; dst = vb; }

  #pragma unroll
  for (int i = 0; i < 2; ++i) {
    int idx = tid + 256 * i;
    int r = idx >> 4, c = (idx & 15) * 4;
    *(float4*)&xs[r][c] = *(const float4*)&x[(size_t)(row0 + r) * EE + c];
  }
  __syncthreads();

  const int col = (tid & 127) * 4;
  const int rg = (tid >> 7) * 16;
  float acc[16][4];
  #pragma unroll
  for (int r = 0; r < 16; ++r)
    #pragma unroll
    for (int j = 0; j < 4; ++j) acc[r][j] = 0.f;

  for (int k = 0; k < EE; k += 4) {
    float4 wr[4];
    #pragma unroll
    for (int j = 0; j < 4; ++j) wr[j] = *(const float4*)&W[(size_t)(k + j) * DD + col];
    #pragma unroll
    for (int r = 0; r < 16; ++r) {
      float4 xv = *(const float4*)&xs[rg + r][k];
      acc[r][0] += xv.x * wr[0].x + xv.y * wr[1].x + xv.z * wr[2].x + xv.w * wr[3].x;
      acc[r][1] += xv.x * wr[0].y + xv.y * wr[1].y + xv.z * wr[2].y + xv.w * wr[3].y;
      acc[r][2] += xv.x * wr[0].z + xv.y * wr[1].z + xv.z * wr[2].z + xv.w * wr[3].z;
      acc[r][3] += xv.x * wr[0].w + xv.y * wr[1].w + xv.z * wr[2].w + xv.w * wr[3].w;
    }
  }

  const float4 b4 = *(const float4*)&bias[col];
  #pragma unroll
  for (int r = 0; r < 16; ++r) {
    ushort4 o;
    o.x = f2h(acc[r][0] + b4.x);
    o.y = f2h(acc[r][1] + b4.y);
    o.z = f2h(acc[r][2] + b4.z);
    o.w = f2h(acc[r][3] + b4.w);
    *(ushort4*)&dst[(size_t)(row0 + rg + r) * DD + col] = o;
  }
}

// ---------------- K2: flash attention v4 (KV-split, 2 blocks/CU) ----------------
// 512 blocks (2/CU), 512 threads (8 waves). Block = (q-pair p, kv-half h).
// Q in regs; swapped QK^T; single-buffered Ks/Vt, reg-staged one tile ahead (T14).
// LDS: Ks[32][512] 32K | Vt[512][40] 40K | Ps[64][40] 5K | stats 1.5K = 78.5K
__global__ __launch_bounds__(512, 4) void attn_fwd(
    const u16* __restrict__ qbuf, const u16* __restrict__ kbuf,
    const u16* __restrict__ vbuf, const float* __restrict__ mask,
    u16* __restrict__ opart, float* __restrict__ stats) {
  extern __shared__ char smem[];
  u16* Ks = (u16*)smem;                       // 32768 B
  u16* Vt = (u16*)(smem + 32768);             // 40960 B
  u16* Ps = (u16*)(smem + 73728);             // 64 x 40 u16
  float* pmx = (float*)(smem + 78848);        // [2][64]
  float* psm = (float*)(smem + 79360);        // [2][64]
  float* alr = (float*)(smem + 79872);        // [64]
  float* lro = (float*)(smem + 80128);        // [64]

  const int tid = threadIdx.x;
  const int lane = tid & 63;
  const int w = tid >> 6;
  const int lrow = lane & 15, lhi = lane >> 4;

  const int bid = blockIdx.x;
  const int p = bid >> 1, h = bid & 1;
  const int xcd = p & 7, slot = p >> 3;
  const int b = xcd >> 1;
  const int q0 = ((xcd & 1) * 32 + slot) * QBLK;
  const int tbase = h * (SS / 2);

  const int qw = w >> 1, tw = w & 1;   // QK: 16 q-rows x 16 t-cols per wave
  const int qw2 = w >> 2, dw = w & 3;  // PV: 32 q-rows x 128 d-cols per wave
  const int row16 = qw * 16 + lrow;
  const int qrow = q0 + row16;

  // ---- Q -> registers (B-operand frags) ----
  f16x8 qreg[16];
  {
    const u16* qg = qbuf + ((size_t)b * SS + qrow) * DD + lhi * 8;
    #pragma unroll
    for (int kk = 0; kk < 16; ++kk) qreg[kk] = *(const f16x8*)(qg + kk * 32);
  }

  // ---- staging registers ----
  const int krow_s = tid & 31;     // K: this thread stages row krow_s, 64B chunk kc
  const int kc = tid >> 5;         // 0..15
  const int vt0l = (tid & 3) * 8;  // V: 8 t x 4 d block
  const int vd0 = (tid >> 2) * 4;
  uint4 kreg[4];
  uint2 vreg[8];

  auto load_kv = [&](int t0n) {
    const u16* kg = kbuf + ((size_t)b * SS + t0n + krow_s) * DD + kc * 32;
    #pragma unroll
    for (int j = 0; j < 4; ++j) kreg[j] = *(const uint4*)(kg + j * 8);
    const u16* vg = vbuf + ((size_t)b * SS + t0n + vt0l) * DD + vd0;
    #pragma unroll
    for (int i = 0; i < 8; ++i) vreg[i] = *(const uint2*)(vg + (size_t)i * DD);
  };

  auto stage_write = [&]() {
    // K: swizzled rows (matches QK read pattern)
    char* kdst = (char*)Ks + krow_s * 1024;
    const int swz = (krow_s & 7) << 4;
    #pragma unroll
    for (int j = 0; j < 4; ++j)
      *(uint4*)(kdst + ((kc * 64 + j * 16) ^ swz)) = kreg[j];
    // V transposed: 4 x ds_write_b128
    #pragma unroll
    for (int e = 0; e < 4; ++e) {
      u32 hh[8];
      #pragma unroll
      for (int i = 0; i < 8; ++i) {
        u32 word = (e < 2) ? vreg[i].x : vreg[i].y;
        hh[i] = (word >> ((e & 1) * 16)) & 0xFFFFu;
      }
      uint4 wv;
      wv.x = hh[0] | (hh[1] << 16);
      wv.y = hh[2] | (hh[3] << 16);
      wv.z = hh[4] | (hh[5] << 16);
      wv.w = hh[6] | (hh[7] << 16);
      *(uint4*)&Vt[(vd0 + e) * 40 + vt0l] = wv;
    }
  };

  float m_reg = -3.0e38f, l_reg = 0.f;
  f32x4 acc[2][8];
  #pragma unroll
  for (int fi = 0; fi < 2; ++fi)
    #pragma unroll
    for (int fj = 0; fj < 8; ++fj) acc[fi][fj] = (f32x4){0.f, 0.f, 0.f, 0.f};

  // ---- prologue: tile 0 -> LDS, tile 1 -> regs ----
  load_kv(tbase);
  stage_write();
  if (NIT2 > 1) load_kv(tbase + KVBLK);
  __syncthreads();

  const int krow_off = (tw * 16 + lrow) * 1024;
  const int kswz = (lrow & 7) << 4;

  #pragma unroll 1
  for (int it = 0; it < NIT2; ++it) {
    const int t0 = tbase + it * KVBLK;

    const size_t mbase = ((size_t)b * SS + qrow) * SS + (size_t)(t0 + tw * 16 + lhi * 4);
    const float4 mv = *(const float4*)&mask[mbase];

    // --- QK^T swapped: s holds S^T -> lane = 4 t-values of q-row `qrow` ---
    f32x4 s = (f32x4){0.f, 0.f, 0.f, 0.f};
    {
      const char* kp = (const char*)Ks + krow_off;
      __builtin_amdgcn_s_setprio(1);
      #pragma unroll
      for (int kk = 0; kk < 16; ++kk) {
        int off = kk * 64 + lhi * 16;
        f16x8 kf = *(const f16x8*)(kp + (off ^ kswz));
        s = __builtin_amdgcn_mfma_f32_16x16x32_f16(kf, qreg[kk], s, 0, 0, 0);
      }
      __builtin_amdgcn_s_setprio(0);
    }
    s[0] += mv.x; s[1] += mv.y; s[2] += mv.z; s[3] += mv.w;

    float pmax = fmaxf(fmaxf(s[0], s[1]), fmaxf(s[2], s[3]));
    pmax = fmaxf(pmax, __shfl_xor(pmax, 16));
    pmax = fmaxf(pmax, __shfl_xor(pmax, 32));
    if (lhi == 0) pmx[tw * 64 + row16] = pmax;
    __syncthreads();  // B1

    const float mt = fmaxf(pmx[row16], pmx[64 + row16]);
    float al;
    if (__any(mt - m_reg > 8.0f)) {  // defer-max
      float mn = fmaxf(m_reg, mt);
      al = __expf(m_reg - mn);
      m_reg = mn;
    } else {
      al = 1.0f;
    }
    const float p0 = __expf(s[0] - m_reg);
    const float p1 = __expf(s[1] - m_reg);
    const float p2 = __expf(s[2] - m_reg);
    const float p3 = __expf(s[3] - m_reg);
    float psum = (p0 + p1) + (p2 + p3);
    psum += __shfl_xor(psum, 16);
    psum += __shfl_xor(psum, 32);
    {
      uint2 pw;
      pw.x = (u32)f2h(p0) | ((u32)f2h(p1) << 16);
      pw.y = (u32)f2h(p2) | ((u32)f2h(p3) << 16);
      *(uint2*)&Ps[row16 * 40 + tw * 16 + lhi * 4] = pw;
    }
    if (lhi == 0) {
      psm[tw * 64 + row16] = psum;
      if (tw == 0) alr[row16] = al;
    }
    __syncthreads();  // B2

    l_reg = al * l_reg + (psm[row16] + psm[64 + row16]);

    {
      float af[2][4];
      #pragma unroll
      for (int fi = 0; fi < 2; ++fi)
        #pragma unroll
        for (int r = 0; r < 4; ++r)
          af[fi][r] = alr[qw2 * 32 + fi * 16 + lhi * 4 + r];
      int ones = (af[0][0] == 1.f) & (af[0][1] == 1.f) & (af[0][2] == 1.f) &
                 (af[0][3] == 1.f) & (af[1][0] == 1.f) & (af[1][1] == 1.f) &
                 (af[1][2] == 1.f) & (af[1][3] == 1.f);
      if (!__all(ones)) {
        #pragma unroll
        for (int fi = 0; fi < 2; ++fi)
          #pragma unroll
          for (int r = 0; r < 4; ++r)
            #pragma unroll
            for (int fj = 0; fj < 8; ++fj) acc[fi][fj][r] *= af[fi][r];
      }
    }

    // --- PV: O += P @ V ---
    {
      f16x8 afr[2];
      afr[0] = *(const f16x8*)&Ps[(qw2 * 32 + lrow) * 40 + lhi * 8];
      afr[1] = *(const f16x8*)&Ps[(qw2 * 32 + 16 + lrow) * 40 + lhi * 8];
      __builtin_amdgcn_s_setprio(1);
      #pragma unroll
      for (int fj = 0; fj < 8; ++fj) {
        f16x8 bf = *(const f16x8*)&Vt[(dw * 128 + fj * 16 + lrow) * 40 + lhi * 8];
        acc[0][fj] = __builtin_amdgcn_mfma_f32_16x16x32_f16(afr[0], bf, acc[0][fj], 0, 0, 0);
        acc[1][fj] = __builtin_amdgcn_mfma_f32_16x16x32_f16(afr[1], bf, acc[1][fj], 0, 0, 0);
      }
      __builtin_amdgcn_s_setprio(0);
    }
    __syncthreads();  // B3: all reads of Ks/Vt/Ps done

    if (it + 1 < NIT2) stage_write();                     // tile it+1 regs -> LDS
    if (it + 2 < NIT2) load_kv(tbase + (it + 2) * KVBLK); // issue tile it+2 -> regs
    __syncthreads();  // B4: LDS writes visible
  }

  // ---- epilogue: per-block normalized partial + (m, l) stats ----
  if (tw == 0 && lhi == 0) {
    lro[row16] = l_reg;
    float2* st = (float2*)stats;
    st[(size_t)h * (BB * SS) + (size_t)b * SS + q0 + row16] = make_float2(m_reg, l_reg);
  }
  __syncthreads();
  #pragma unroll
  for (int fi = 0; fi < 2; ++fi) {
    #pragma unroll
    for (int r = 0; r < 4; ++r) {
      int row = qw2 * 32 + fi * 16 + lhi * 4 + r;
      float rl = 1.0f / lro[row];
      size_t base = ((size_t)h * (BB * SS) + (size_t)b * SS + (size_t)(q0 + row)) * DD +
                    (size_t)(dw * 128 + lrow);
      #pragma unroll
      for (int fj = 0; fj < 8; ++fj) opart[base + fj * 16] = f2h(acc[fi][fj][r] * rl);
    }
  }
}

// ---------------- K2b: merge the two KV-halves ----------------
__global__ __launch_bounds__(256) void merge_halves(
    const u16* __restrict__ opart, const float* __restrict__ stats,
    u16* __restrict__ zbuf) {
  const int gid = blockIdx.x * 256 + threadIdx.x;
  const int row = gid >> 6;
  const int c = gid & 63;
  const float2* st = (const float2*)stats;
  const float2 A = st[row];
  const float2 Bs = st[BB * SS + row];
  const float m = fmaxf(A.x, Bs.x);
  const float sa = __expf(A.x - m) * A.y;
  const float sb = __expf(Bs.x - m) * Bs.y;
  const float inv = 0.35355339059327373f / (sa + sb);
  const float wa = sa * inv, wb = sb * inv;
  const size_t off = (size_t)row * DD + (size_t)c * 8;
  uint4 ua = *(const uint4*)(opart + off);
  uint4 ub = *(const uint4*)(opart + (size_t)BB * SS * DD + off);
  union { uint4 u; u16 hh[8]; } ca, cb, co;
  ca.u = ua; cb.u = ub;
  #pragma unroll
  for (int e = 0; e < 8; ++e)
    co.hh[e] = f2h(wa * h2f(ca.hh[e]) + wb * h2f(cb.hh[e]));
  *(uint4*)(zbuf + off) = co.u;
}

// ---------------- K3: out = z @ Wo + bo (fp32 VALU) ----------------
__global__ __launch_bounds__(256) void out_proj(
    const u16* __restrict__ zbuf, const float* __restrict__ Wo,
    const float* __restrict__ bo, float* __restrict__ out) {
  __shared__ float zs[32][DD];
  const int tid = threadIdx.x;
  const int row0 = blockIdx.x * 32;
  #pragma unroll
  for (int i = 0; i < 8; ++i) {
    int idx = tid + 256 * i;
    int r = idx >> 6, off = (idx & 63) * 8;
    uint4 u = *(const uint4*)(zbuf + (size_t)(row0 + r) * DD + off);
    union { uint4 uu; u16 hh[8]; } cv;
    cv.uu = u;
    #pragma unroll
    for (int e = 0; e < 8; ++e) zs[r][off + e] = h2f(cv.hh[e]);
  }
  __syncthreads();

  const int col = tid & 63;
  const int rg = (tid >> 6) * 8;
  float acc[8];
  #pragma unroll
  for (int r = 0; r < 8; ++r) acc[r] = 0.f;

  for (int k = 0; k < DD; k += 4) {
    float w0 = Wo[(size_t)k * EE + col];
    float w1 = Wo[(size_t)(k + 1) * EE + col];
    float w2 = Wo[(size_t)(k + 2) * EE + col];
    float w3 = Wo[(size_t)(k + 3) * EE + col];
    #pragma unroll
    for (int r = 0; r < 8; ++r) {
      float4 z4 = *(const float4*)&zs[rg + r][k];
      acc[r] += z4.x * w0 + z4.y * w1 + z4.z * w2 + z4.w * w3;
    }
  }
  float bv = bo[col];
  #pragma unroll
  for (int r = 0; r < 8; ++r)
    out[(size_t)(row0 + rg + r) * EE + col] = acc[r] + bv;
}

extern "C" void kernel_launch(void* const* d_in, const int* in_sizes, int n_in,
                              void* d_out, int out_size, void* d_ws, size_t ws_size,
                              hipStream_t stream) {
  const float* x = (const float*)d_in[0];
  const float* mask = (const float*)d_in[1];
  const float* Wq = (const float*)d_in[2];
  const float* bq = (const float*)d_in[3];
  const float* Wk = (const float*)d_in[4];
  const float* bk = (const float*)d_in[5];
  const float* Wv = (const float*)d_in[6];
  const float* bv = (const float*)d_in[7];
  const float* Wo = (const float*)d_in[8];
  const float* bo = (const float*)d_in[9];
  float* out = (float*)d_out;

  const size_t N = (size_t)BB * SS * DD;
  u16* qb = (u16*)d_ws;
  u16* kb = qb + N;
  u16* vb = kb + N;
  u16* zb = vb + N;
  u16* op = zb + N;            // 2*N u16
  float* st = (float*)(op + 2 * N);  // float2[2][BB*SS]

  qkv_proj<<<dim3(BB * SS / 32, 3), 256, 0, stream>>>(x, Wq, bq, Wk, bk, Wv, bv, qb, kb, vb);

  attn_fwd<<<512, 512, 80384, stream>>>(qb, kb, vb, mask, op, st);

  merge_halves<<<BB * SS * 64 / 256, 256, 0, stream>>>(op, st, zb);

  out_proj<<<BB * SS / 32, 256, 0, stream>>>(zb, Wo, bo, out);
}

// Round 7
// 509.073 us; speedup vs baseline: 2.6874x; 2.6874x over previous
//
#include <hip/hip_runtime.h>
#include <hip/hip_bf16.h>

#define BB 4
#define SS 4096
#define EE 64
#define DD 512
#define KVBLK 32
#define NITH 64  // tiles per block (half the KV range)

typedef __attribute__((ext_vector_type(4))) float f32x4;
typedef __attribute__((ext_vector_type(8))) _Float16 f16x8;
typedef unsigned short u16;
typedef unsigned int u32;

__device__ __forceinline__ u16 f2h(float f) {
  _Float16 h = (_Float16)f;
  return __builtin_bit_cast(u16, h);
}
__device__ __forceinline__ float h2f(u16 b) {
  return (float)__builtin_bit_cast(_Float16, b);
}

__device__ __forceinline__ void async16(const void* g, void* l) {
  __builtin_amdgcn_global_load_lds(
      (const __attribute__((address_space(1))) void*)g,
      (__attribute__((address_space(3))) void*)l, 16, 0, 0);
}

// ---------------- K1: qkv projection (fp32 VALU), emit fp16 ----------------
__global__ __launch_bounds__(256) void qkv_proj(
    const float* __restrict__ x,
    const float* __restrict__ Wq, const float* __restrict__ bq,
    const float* __restrict__ Wk, const float* __restrict__ bk,
    const float* __restrict__ Wv, const float* __restrict__ bv,
    u16* __restrict__ qb, u16* __restrict__ kb, u16* __restrict__ vb) {
  __shared__ float xs[32][EE];
  const int tid = threadIdx.x;
  const int row0 = blockIdx.x * 32;
  const float* W;
  const float* bias;
  u16* dst;
  if (blockIdx.y == 0) { W = Wq; bias = bq; dst = qb; }
  else if (blockIdx.y == 1) { W = Wk; bias = bk; dst = kb; }
  else { W = Wv; bias = bv; dst = vb; }

  #pragma unroll
  for (int i = 0; i < 2; ++i) {
    int idx = tid + 256 * i;
    int r = idx >> 4, c = (idx & 15) * 4;
    *(float4*)&xs[r][c] = *(const float4*)&x[(size_t)(row0 + r) * EE + c];
  }
  __syncthreads();

  const int col = (tid & 127) * 4;
  const int rg = (tid >> 7) * 16;
  float acc[16][4];
  #pragma unroll
  for (int r = 0; r < 16; ++r)
    #pragma unroll
    for (int j = 0; j < 4; ++j) acc[r][j] = 0.f;

  for (int k = 0; k < EE; k += 4) {
    float4 wr[4];
    #pragma unroll
    for (int j = 0; j < 4; ++j) wr[j] = *(const float4*)&W[(size_t)(k + j) * DD + col];
    #pragma unroll
    for (int r = 0; r < 16; ++r) {
      float4 xv = *(const float4*)&xs[rg + r][k];
      acc[r][0] += xv.x * wr[0].x + xv.y * wr[1].x + xv.z * wr[2].x + xv.w * wr[3].x;
      acc[r][1] += xv.x * wr[0].y + xv.y * wr[1].y + xv.z * wr[2].y + xv.w * wr[3].y;
      acc[r][2] += xv.x * wr[0].z + xv.y * wr[1].z + xv.z * wr[2].z + xv.w * wr[3].z;
      acc[r][3] += xv.x * wr[0].w + xv.y * wr[1].w + xv.z * wr[2].w + xv.w * wr[3].w;
    }
  }

  const float4 b4 = *(const float4*)&bias[col];
  #pragma unroll
  for (int r = 0; r < 16; ++r) {
    ushort4 o;
    o.x = f2h(acc[r][0] + b4.x);
    o.y = f2h(acc[r][1] + b4.y);
    o.z = f2h(acc[r][2] + b4.z);
    o.w = f2h(acc[r][3] + b4.w);
    *(ushort4*)&dst[(size_t)(row0 + rg + r) * DD + col] = o;
  }
}

// ---------------- K2: flash attention v5 (warp-private softmax) ----------------
// 256 blocks (1/CU), 512 threads (8 waves). Block = (q-tile, batch, kv-half).
// bid&7 = (batch, half) so each XCD's 32 blocks share one K/V-half in L2.
// Each warp owns 16 q-rows end-to-end: QK^T (2 chains), softmax (in-warp),
// P via warp-private LDS, PV (32 indep chains). 1 barrier + 1 vmcnt per tile.
// LDS: Ks[2][32][512] 64K | Vt[2][512][40] 80K | Ps[8][16][36] 9K = 153K
__global__ __launch_bounds__(512, 2) void attn_fwd(
    const u16* __restrict__ qbuf, const u16* __restrict__ kbuf,
    const u16* __restrict__ vbuf, const float* __restrict__ mask,
    u16* __restrict__ opart, float* __restrict__ stats) {
  extern __shared__ char smem[];
  // Ks: bytes [0, 65536); Vt: [65536, 147456); Ps: [147456, 156672)
  u16* PsAll = (u16*)(smem + 147456);

  const int tid = threadIdx.x;
  const int lane = tid & 63;
  const int w = tid >> 6;
  const int lrow = lane & 15, lhi = lane >> 4;

  const int bid = blockIdx.x;
  const int grp = bid & 7;          // XCD group
  const int b = grp >> 1, h = grp & 1;
  const int q0 = (bid >> 3) * 128;  // 32 q-tiles x 128 rows
  const int tbase = h * (SS / 2);

  const int qrow = q0 + w * 16 + lrow;  // this lane's q-row (within batch b)

  // ---- Q -> registers (B-operand frags) ----
  f16x8 qreg[16];
  {
    const u16* qg = qbuf + ((size_t)b * SS + qrow) * DD + lhi * 8;
    #pragma unroll
    for (int kk = 0; kk < 16; ++kk) qreg[kk] = *(const f16x8*)(qg + kk * 32);
  }

  // ---- staging helpers ----
  const int vt0l = (tid & 3) * 8;   // V: 8 t x 4 d block per thread
  const int vd0 = (tid >> 2) * 4;
  uint2 vreg[8];

  auto stage_k = [&](int t0n, int buf) {
    const char* kg = (const char*)(kbuf + ((size_t)b * SS + t0n) * DD);
    char* kd = (char*)smem + buf * 32768;
    #pragma unroll
    for (int rr = 0; rr < 4; ++rr) {
      int row = w + rr * 8;
      async16(kg + (size_t)row * 1024 + ((lane * 16) ^ ((row & 7) << 4)),
              kd + row * 1024);
    }
  };
  auto load_v = [&](int t0n) {
    const u16* vg = vbuf + ((size_t)b * SS + t0n + vt0l) * DD + vd0;
    #pragma unroll
    for (int i = 0; i < 8; ++i) vreg[i] = *(const uint2*)(vg + (size_t)i * DD);
  };
  auto write_vt = [&](int buf) {
    u16* dst = (u16*)(smem + 65536 + buf * 40960);
    #pragma unroll
    for (int e = 0; e < 4; ++e) {
      u32 hh[8];
      #pragma unroll
      for (int i = 0; i < 8; ++i) {
        u32 word = (e < 2) ? vreg[i].x : vreg[i].y;
        hh[i] = (word >> ((e & 1) * 16)) & 0xFFFFu;
      }
      uint4 wv;
      wv.x = hh[0] | (hh[1] << 16);
      wv.y = hh[2] | (hh[3] << 16);
      wv.z = hh[4] | (hh[5] << 16);
      wv.w = hh[6] | (hh[7] << 16);
      *(uint4*)&dst[(vd0 + e) * 40 + vt0l] = wv;
    }
  };

  float m_reg = -3.0e38f, l_reg = 0.f;
  f32x4 acc[32];
  #pragma unroll
  for (int f = 0; f < 32; ++f) acc[f] = (f32x4){0.f, 0.f, 0.f, 0.f};

  // ---- prologue: K0 async, V0 regs -> LDS ----
  stage_k(tbase, 0);
  load_v(tbase);
  asm volatile("s_waitcnt vmcnt(0)" ::: "memory");
  write_vt(0);
  __syncthreads();

  u16* PsW = PsAll + w * 576;  // warp-private [16][36]
  const int kswz = (lrow & 7) << 4;

  #pragma unroll 1
  for (int it = 0; it < NITH; ++it) {
    const int buf = it & 1;
    const int t0 = tbase + it * KVBLK;

    // --- prefetch next tile (K async -> buf^1, V -> regs) ---
    if (it + 1 < NITH) {
      stage_k(t0 + KVBLK, buf ^ 1);
      load_v(t0 + KVBLK);
    }
    // --- mask for current tile (consumed after QK chain) ---
    const size_t mrow = ((size_t)b * SS + qrow) * SS + (size_t)t0;
    const float4 cA = *(const float4*)&mask[mrow + lhi * 4];
    const float4 cB = *(const float4*)&mask[mrow + 16 + lhi * 4];

    // --- QK^T swapped, both 16-t halves in-warp (2 indep chains) ---
    f32x4 s0 = (f32x4){0.f, 0.f, 0.f, 0.f};
    f32x4 s1 = (f32x4){0.f, 0.f, 0.f, 0.f};
    {
      const char* kp0 = (const char*)smem + buf * 32768 + lrow * 1024;
      const char* kp1 = kp0 + 16384;
      __builtin_amdgcn_s_setprio(1);
      #pragma unroll
      for (int kk = 0; kk < 16; ++kk) {
        int off = kk * 64 + lhi * 16;
        f16x8 k0 = *(const f16x8*)(kp0 + (off ^ kswz));
        f16x8 k1 = *(const f16x8*)(kp1 + (off ^ kswz));
        s0 = __builtin_amdgcn_mfma_f32_16x16x32_f16(k0, qreg[kk], s0, 0, 0, 0);
        s1 = __builtin_amdgcn_mfma_f32_16x16x32_f16(k1, qreg[kk], s1, 0, 0, 0);
      }
      __builtin_amdgcn_s_setprio(0);
    }
    s0[0] += cA.x; s0[1] += cA.y; s0[2] += cA.z; s0[3] += cA.w;
    s1[0] += cB.x; s1[1] += cB.y; s1[2] += cB.z; s1[3] += cB.w;

    // --- in-warp softmax: q = lane&15, t spread over lhi + 8 slots ---
    float pmax = fmaxf(fmaxf(fmaxf(s0[0], s0[1]), fmaxf(s0[2], s0[3])),
                       fmaxf(fmaxf(s1[0], s1[1]), fmaxf(s1[2], s1[3])));
    pmax = fmaxf(pmax, __shfl_xor(pmax, 16));
    pmax = fmaxf(pmax, __shfl_xor(pmax, 32));

    if (__any(pmax - m_reg > 8.0f)) {  // defer-max (T13)
      float mn = fmaxf(m_reg, pmax);
      float al = __expf(m_reg - mn);
      m_reg = mn;
      l_reg *= al;
      float av[4];
      #pragma unroll
      for (int r = 0; r < 4; ++r) av[r] = __shfl(al, lhi * 4 + r);
      #pragma unroll
      for (int f = 0; f < 32; ++f)
        #pragma unroll
        for (int r = 0; r < 4; ++r) acc[f][r] *= av[r];
    }

    float p[8];
    #pragma unroll
    for (int r = 0; r < 4; ++r) p[r] = __expf(s0[r] - m_reg);
    #pragma unroll
    for (int r = 0; r < 4; ++r) p[4 + r] = __expf(s1[r] - m_reg);
    float psum = ((p[0] + p[1]) + (p[2] + p[3])) + ((p[4] + p[5]) + (p[6] + p[7]));
    psum += __shfl_xor(psum, 16);
    psum += __shfl_xor(psum, 32);
    l_reg += psum;

    // --- P -> warp-private LDS (no barrier; same-wave round trip) ---
    {
      uint2 pw0, pw1;
      pw0.x = (u32)f2h(p[0]) | ((u32)f2h(p[1]) << 16);
      pw0.y = (u32)f2h(p[2]) | ((u32)f2h(p[3]) << 16);
      pw1.x = (u32)f2h(p[4]) | ((u32)f2h(p[5]) << 16);
      pw1.y = (u32)f2h(p[6]) | ((u32)f2h(p[7]) << 16);
      *(uint2*)&PsW[lrow * 36 + lhi * 4] = pw0;
      *(uint2*)&PsW[lrow * 36 + 16 + lhi * 4] = pw1;
    }
    f16x8 pa = *(const f16x8*)&PsW[lrow * 36 + lhi * 8];

    // --- PV: O += P @ V (32 independent chains) ---
    {
      const u16* vt = (const u16*)(smem + 65536 + buf * 40960);
      __builtin_amdgcn_s_setprio(1);
      #pragma unroll
      for (int f = 0; f < 32; ++f) {
        f16x8 bf = *(const f16x8*)&vt[(f * 16 + lrow) * 40 + lhi * 8];
        acc[f] = __builtin_amdgcn_mfma_f32_16x16x32_f16(pa, bf, acc[f], 0, 0, 0);
      }
      __builtin_amdgcn_s_setprio(0);
    }

    // --- tile end: drain prefetch, stage next V, single barrier ---
    asm volatile("s_waitcnt vmcnt(0)" ::: "memory");
    if (it + 1 < NITH) write_vt(buf ^ 1);
    __syncthreads();
  }

  // ---- epilogue: normalized partial + (m, l) stats ----
  if (lane < 16) {
    float2* st = (float2*)stats;
    st[(size_t)h * (BB * SS) + (size_t)b * SS + q0 + w * 16 + lane] =
        make_float2(m_reg, l_reg);
  }
  float rl[4];
  #pragma unroll
  for (int r = 0; r < 4; ++r) rl[r] = 1.0f / __shfl(l_reg, lhi * 4 + r);
  #pragma unroll
  for (int r = 0; r < 4; ++r) {
    size_t base = ((size_t)h * (BB * SS) + (size_t)b * SS +
                   (size_t)(q0 + w * 16 + lhi * 4 + r)) * DD + (size_t)lrow;
    #pragma unroll
    for (int f = 0; f < 32; ++f) opart[base + f * 16] = f2h(acc[f][r] * rl[r]);
  }
}

// ---------------- K2b: merge the two KV-halves ----------------
__global__ __launch_bounds__(256) void merge_halves(
    const u16* __restrict__ opart, const float* __restrict__ stats,
    u16* __restrict__ zbuf) {
  const int gid = blockIdx.x * 256 + threadIdx.x;
  const int row = gid >> 6;
  const int c = gid & 63;
  const float2* st = (const float2*)stats;
  const float2 A = st[row];
  const float2 Bs = st[BB * SS + row];
  const float m = fmaxf(A.x, Bs.x);
  const float sa = __expf(A.x - m) * A.y;
  const float sb = __expf(Bs.x - m) * Bs.y;
  const float inv = 0.35355339059327373f / (sa + sb);
  const float wa = sa * inv, wb = sb * inv;
  const size_t off = (size_t)row * DD + (size_t)c * 8;
  uint4 ua = *(const uint4*)(opart + off);
  uint4 ub = *(const uint4*)(opart + (size_t)BB * SS * DD + off);
  union { uint4 u; u16 hh[8]; } ca, cb, co;
  ca.u = ua; cb.u = ub;
  #pragma unroll
  for (int e = 0; e < 8; ++e)
    co.hh[e] = f2h(wa * h2f(ca.hh[e]) + wb * h2f(cb.hh[e]));
  *(uint4*)(zbuf + off) = co.u;
}

// ---------------- K3: out = z @ Wo + bo (fp32 VALU) ----------------
__global__ __launch_bounds__(256) void out_proj(
    const u16* __restrict__ zbuf, const float* __restrict__ Wo,
    const float* __restrict__ bo, float* __restrict__ out) {
  __shared__ float zs[32][DD];
  const int tid = threadIdx.x;
  const int row0 = blockIdx.x * 32;
  #pragma unroll
  for (int i = 0; i < 8; ++i) {
    int idx = tid + 256 * i;
    int r = idx >> 6, off = (idx & 63) * 8;
    uint4 u = *(const uint4*)(zbuf + (size_t)(row0 + r) * DD + off);
    union { uint4 uu; u16 hh[8]; } cv;
    cv.uu = u;
    #pragma unroll
    for (int e = 0; e < 8; ++e) zs[r][off + e] = h2f(cv.hh[e]);
  }
  __syncthreads();

  const int col = tid & 63;
  const int rg = (tid >> 6) * 8;
  float acc[8];
  #pragma unroll
  for (int r = 0; r < 8; ++r) acc[r] = 0.f;

  for (int k = 0; k < DD; k += 4) {
    float w0 = Wo[(size_t)k * EE + col];
    float w1 = Wo[(size_t)(k + 1) * EE + col];
    float w2 = Wo[(size_t)(k + 2) * EE + col];
    float w3 = Wo[(size_t)(k + 3) * EE + col];
    #pragma unroll
    for (int r = 0; r < 8; ++r) {
      float4 z4 = *(const float4*)&zs[rg + r][k];
      acc[r] += z4.x * w0 + z4.y * w1 + z4.z * w2 + z4.w * w3;
    }
  }
  float bv = bo[col];
  #pragma unroll
  for (int r = 0; r < 8; ++r)
    out[(size_t)(row0 + rg + r) * EE + col] = acc[r] + bv;
}

extern "C" void kernel_launch(void* const* d_in, const int* in_sizes, int n_in,
                              void* d_out, int out_size, void* d_ws, size_t ws_size,
                              hipStream_t stream) {
  const float* x = (const float*)d_in[0];
  const float* mask = (const float*)d_in[1];
  const float* Wq = (const float*)d_in[2];
  const float* bq = (const float*)d_in[3];
  const float* Wk = (const float*)d_in[4];
  const float* bk = (const float*)d_in[5];
  const float* Wv = (const float*)d_in[6];
  const float* bv = (const float*)d_in[7];
  const float* Wo = (const float*)d_in[8];
  const float* bo = (const float*)d_in[9];
  float* out = (float*)d_out;

  const size_t N = (size_t)BB * SS * DD;
  u16* qb = (u16*)d_ws;
  u16* kb = qb + N;
  u16* vb = kb + N;
  u16* zb = vb + N;
  u16* op = zb + N;                  // 2*N u16
  float* st = (float*)(op + 2 * N);  // float2[2][BB*SS]

  qkv_proj<<<dim3(BB * SS / 32, 3), 256, 0, stream>>>(x, Wq, bq, Wk, bk, Wv, bv, qb, kb, vb);

  attn_fwd<<<256, 512, 156672, stream>>>(qb, kb, vb, mask, op, st);

  merge_halves<<<BB * SS * 64 / 256, 256, 0, stream>>>(op, st, zb);

  out_proj<<<BB * SS / 32, 256, 0, stream>>>(zb, Wo, bo, out);
}